// Round 1
// baseline (243.568 us; speedup 1.0000x reference)
//
#include <hip/hip_runtime.h>
#include <hip/hip_bf16.h>

// GlobalGatedUpdater:
//   out[b, i, :] = emb[i, :]                                   if i not in idx_b[b]
//   out[b, i, :] = (1-alpha[i])*emb[i,:] + alpha[i]*feat[b,j,:] for j = LAST pos with idx_b[b][j]==i
//
// B=16 graphs, n=50 idx/graph, items=50000, DIM=64 (16 float4 segments/row).
// Strategy: fused single pass. Per-block LDS bitmap (items bits = 6.25 KB) marks
// touched rows in O(1); only touched rows (~0.1%) do the 50-entry last-match scan.
// All global traffic is contiguous float4 -> HBM-write-bound (~205 MB out).

#define DIM 64
#define SEGS (DIM / 4)      // 16 float4 per row
#define BLOCK 256
#define ROWS_PER_BLOCK 512  // rows of one graph handled per block

__global__ __launch_bounds__(BLOCK) void ggu_kernel(
    const int* __restrict__ nodes,        // (B*n)
    const float4* __restrict__ feat,      // (B*n, SEGS)
    const float4* __restrict__ emb,       // (items, SEGS)
    const float* __restrict__ alpha,      // (items)
    float4* __restrict__ out,             // (B, items, SEGS)
    int items, int n, int blocks_per_graph)
{
    const int b     = blockIdx.x / blocks_per_graph;
    const int chunk = blockIdx.x % blocks_per_graph;
    const int row0  = chunk * ROWS_PER_BLOCK;

    extern __shared__ unsigned int smem[];
    const int nwords = (items + 31) >> 5;
    unsigned int* bitmap = smem;           // nwords words
    int* sidx = (int*)(smem + nwords);     // n words

    // Build this graph's presence bitmap + cached index list.
    for (int w = threadIdx.x; w < nwords; w += BLOCK) bitmap[w] = 0u;
    __syncthreads();
    for (int j = threadIdx.x; j < n; j += BLOCK) {
        int id = nodes[b * n + j];
        sidx[j] = id;
        atomicOr(&bitmap[id >> 5], 1u << (id & 31));
    }
    __syncthreads();

    const int seg  = threadIdx.x & (SEGS - 1);   // which float4 of the row
    const int rloc = threadIdx.x >> 4;           // row within iteration (0..15)
    const int rows_per_iter = BLOCK >> 4;        // 16
    const int rend = min(row0 + ROWS_PER_BLOCK, items);

    const size_t out_base = (size_t)b * items * SEGS;

    for (int r = row0 + rloc; r < rend; r += rows_per_iter) {
        float4 e = emb[(size_t)r * SEGS + seg];
        unsigned int w = bitmap[r >> 5];
        if (w & (1u << (r & 31))) {
            // rare path: find LAST j with idx==r (last-write-wins semantics)
            int jlast = -1;
            #pragma unroll 1
            for (int j = 0; j < n; ++j)
                if (sidx[j] == r) jlast = j;
            float a = alpha[r];
            float4 f = feat[(size_t)(b * n + jlast) * SEGS + seg];
            float om = 1.0f - a;
            e.x = om * e.x + a * f.x;
            e.y = om * e.y + a * f.y;
            e.z = om * e.z + a * f.z;
            e.w = om * e.w + a * f.w;
        }
        out[out_base + (size_t)r * SEGS + seg] = e;
    }
}

extern "C" void kernel_launch(void* const* d_in, const int* in_sizes, int n_in,
                              void* d_out, int out_size, void* d_ws, size_t ws_size,
                              hipStream_t stream) {
    const int*   nodes = (const int*)d_in[0];
    const float* feat  = (const float*)d_in[1];
    const float* emb   = (const float*)d_in[2];
    const float* alpha = (const float*)d_in[3];
    // d_in[4] = n_per_graph scalar (device); derive sizes host-side instead
    // (no device reads allowed under graph capture).

    const int items = in_sizes[3];                   // alpha: (items, 1) -> 50000
    const int B     = out_size / (items * DIM);      // 16
    const int total_nodes = in_sizes[0];             // B*n = 800
    const int n     = total_nodes / B;               // 50

    const int blocks_per_graph = (items + ROWS_PER_BLOCK - 1) / ROWS_PER_BLOCK;  // 98
    const int grid = B * blocks_per_graph;                                        // 1568

    const int nwords = (items + 31) >> 5;            // 1563
    const size_t lds_bytes = (size_t)(nwords + n) * sizeof(unsigned int);  // ~6.4 KB

    ggu_kernel<<<grid, BLOCK, lds_bytes, stream>>>(
        nodes, (const float4*)feat, (const float4*)emb, alpha,
        (float4*)d_out, items, n, blocks_per_graph);
}

// Round 2
// 233.321 us; speedup vs baseline: 1.0439x; 1.0439x over previous
//
#include <hip/hip_runtime.h>
#include <hip/hip_bf16.h>

// GlobalGatedUpdater, round 2: graph-loop-inside structure.
//   out[b, i, :] = emb[i, :]                                    (i untouched in graph b)
//   out[b, i, :] = (1-alpha[i])*emb[i,:] + alpha[i]*feat[b,jlast,:]  (jlast = LAST pos of i)
//
// R1 post-mortem: graph-per-block re-read emb 16x (204.8 MB extra) -> ~120 us.
// Now each block owns RPB rows and serves ALL B graphs: emb read ONCE (12.8 MB),
// each float4 held in registers and stored B times (204.8 MB writes, the floor).
// Presence test: per-row B-bit mask in LDS (bit b = row touched in graph b),
// built by scanning all B*n node ids (3.2 KB, L2-hit). Requires B <= 32 (B=16).
// Nontemporal stores: out is write-once, keep it out of L2.

#define DIM 64
#define SEGS (DIM / 4)      // 16 float4 per row
#define BLOCK 256
#define RPB 32              // rows per block -> grid 1563 (~6 blocks/CU)

typedef float v4f __attribute__((ext_vector_type(4)));

__device__ __forceinline__ void nt_store(float4* p, const float4& v) {
    __builtin_nontemporal_store(*(const v4f*)&v, (v4f*)p);
}

template <int CB>  // CB = compile-time B (0 = runtime fallback)
__global__ __launch_bounds__(BLOCK) void ggu_kernel(
    const int* __restrict__ nodes,        // (B*n)
    const float4* __restrict__ feat,      // (B*n, SEGS)
    const float4* __restrict__ emb,       // (items, SEGS)
    const float* __restrict__ alpha,      // (items)
    float4* __restrict__ out,             // (B, items, SEGS)
    int items, int n, int Brt)
{
    const int B = (CB > 0) ? CB : Brt;
    const int row0 = blockIdx.x * RPB;

    extern __shared__ unsigned int smem[];
    unsigned int* rowmask = smem;          // RPB words: bit b => row touched in graph b
    int* sidx = (int*)(smem + RPB);        // B*n cached node ids

    const int total = B * n;
    if (threadIdx.x < RPB) rowmask[threadIdx.x] = 0u;
    __syncthreads();
    for (int t = threadIdx.x; t < total; t += BLOCK) {
        int id = nodes[t];
        sidx[t] = id;
        int local = id - row0;
        if ((unsigned)local < (unsigned)RPB)
            atomicOr(&rowmask[local], 1u << (t / n));
    }
    __syncthreads();

    const int seg  = threadIdx.x & (SEGS - 1);   // float4 within row
    const int rloc = threadIdx.x >> 4;           // 0..15: row within iteration
    const int rend = min(row0 + RPB, items);
    const size_t bstride = (size_t)items * SEGS; // float4 stride between graphs

    for (int r = row0 + rloc; r < rend; r += (BLOCK / SEGS)) {
        const float4 e = emb[(size_t)r * SEGS + seg];
        const unsigned int mask = rowmask[r - row0];
        float4* po = out + (size_t)r * SEGS + seg;

        if (mask == 0u) {
            // common path (~98.4% of rows): broadcast emb row to all graphs
            #pragma unroll
            for (int b = 0; b < ((CB > 0) ? CB : 1); ++b) {
                if (CB > 0) { nt_store(po, e); po += bstride; }
            }
            if (CB == 0) {
                for (int b = 0; b < B; ++b) { nt_store(po, e); po += bstride; }
            }
        } else {
            const float a  = alpha[r];
            const float om = 1.0f - a;
            for (int b = 0; b < B; ++b) {
                float4 v = e;
                if ((mask >> b) & 1u) {
                    int jlast = 0;  // mask bit set => at least one match exists
                    #pragma unroll 1
                    for (int j = 0; j < n; ++j)
                        if (sidx[b * n + j] == r) jlast = j;   // last-write-wins
                    const float4 f = feat[(size_t)(b * n + jlast) * SEGS + seg];
                    v.x = om * e.x + a * f.x;
                    v.y = om * e.y + a * f.y;
                    v.z = om * e.z + a * f.z;
                    v.w = om * e.w + a * f.w;
                }
                nt_store(po, v);
                po += bstride;
            }
        }
    }
}

extern "C" void kernel_launch(void* const* d_in, const int* in_sizes, int n_in,
                              void* d_out, int out_size, void* d_ws, size_t ws_size,
                              hipStream_t stream) {
    const int*   nodes = (const int*)d_in[0];
    const float* feat  = (const float*)d_in[1];
    const float* emb   = (const float*)d_in[2];
    const float* alpha = (const float*)d_in[3];

    const int items = in_sizes[3];                 // 50000
    const int B     = out_size / (items * DIM);    // 16
    const int n     = in_sizes[0] / B;             // 50

    const int grid = (items + RPB - 1) / RPB;      // 1563
    const size_t lds_bytes = (size_t)(RPB + B * n) * sizeof(unsigned int); // ~3.3 KB

    if (B == 16) {
        ggu_kernel<16><<<grid, BLOCK, lds_bytes, stream>>>(
            nodes, (const float4*)feat, (const float4*)emb, alpha,
            (float4*)d_out, items, n, B);
    } else {
        ggu_kernel<0><<<grid, BLOCK, lds_bytes, stream>>>(
            nodes, (const float4*)feat, (const float4*)emb, alpha,
            (float4*)d_out, items, n, B);
    }
}

// Round 3
// 215.996 us; speedup vs baseline: 1.1276x; 1.0802x over previous
//
#include <hip/hip_runtime.h>
#include <hip/hip_bf16.h>

// GlobalGatedUpdater, round 3: graph-loop OUTERMOST for write-stream locality.
//
// R2 post-mortem: `for b: store` innermost interleaved 1 KB bursts across 16
// streams 12.8 MB apart (~24k concurrent write streams chip-wide) -> DRAM
// row-buffer thrash, ~2.9 TB/s effective vs the 6.45 TB/s the harness fill
// demonstrates. Now: block's 32 rows live in registers (2 float4/thread),
// graph loop outer -> one 8 KB contiguous burst per graph per block, ~1.5k
// concurrent streams. Plain stores (match the fill's path), no NT flag.

#define DIM 64
#define SEGS (DIM / 4)      // 16 float4 per row
#define BLOCK 256
#define RPB 32              // rows per block -> grid 1563, 8 KB burst/graph

template <int CB>  // CB = compile-time B (0 = runtime fallback)
__global__ __launch_bounds__(BLOCK) void ggu_kernel(
    const int* __restrict__ nodes,        // (B*n)
    const float4* __restrict__ feat,      // (B*n, SEGS)
    const float4* __restrict__ emb,       // (items, SEGS)
    const float* __restrict__ alpha,      // (items)
    float4* __restrict__ out,             // (B, items, SEGS)
    int items, int n, int Brt)
{
    const int B = (CB > 0) ? CB : Brt;
    const int row0 = blockIdx.x * RPB;

    extern __shared__ unsigned int smem[];
    unsigned int* rowmask = smem;          // RPB words: bit b => row touched in graph b
    int* sidx = (int*)(smem + RPB);        // B*n cached node ids

    const int total = B * n;
    if (threadIdx.x < RPB) rowmask[threadIdx.x] = 0u;
    __syncthreads();
    for (int t = threadIdx.x; t < total; t += BLOCK) {
        int id = nodes[t];
        sidx[t] = id;
        int local = id - row0;
        if ((unsigned)local < (unsigned)RPB)
            atomicOr(&rowmask[local], 1u << (t / n));
    }
    __syncthreads();

    const int seg  = threadIdx.x & (SEGS - 1);   // float4 within row
    const int rloc = threadIdx.x >> 4;           // 0..15
    const int r0 = row0 + rloc;                  // first owned row
    const int r1 = r0 + 16;                      // second owned row
    const bool ok0 = r0 < items;
    const bool ok1 = r1 < items;

    // Load the block's 32 rows into registers (one seg per thread per row).
    float4 e0 = ok0 ? emb[(size_t)r0 * SEGS + seg] : float4{0, 0, 0, 0};
    float4 e1 = ok1 ? emb[(size_t)r1 * SEGS + seg] : float4{0, 0, 0, 0};
    const unsigned int m0 = ok0 ? rowmask[rloc] : 0u;
    const unsigned int m1 = ok1 ? rowmask[rloc + 16] : 0u;

    const size_t bstride = (size_t)items * SEGS;           // float4 stride / graph
    float4* po0 = out + (size_t)r0 * SEGS + seg;
    float4* po1 = out + (size_t)r1 * SEGS + seg;

    if ((m0 | m1) == 0u) {
        // Common path (~99% of wave-rows): pure broadcast, B contiguous bursts.
        if (CB > 0) {
            #pragma unroll
            for (int b = 0; b < CB; ++b) {
                if (ok0) po0[b * bstride] = e0;
                if (ok1) po1[b * bstride] = e1;
            }
        } else {
            for (int b = 0; b < B; ++b) {
                if (ok0) po0[b * bstride] = e0;
                if (ok1) po1[b * bstride] = e1;
            }
        }
    } else {
        const float a0 = ok0 ? alpha[r0] : 0.0f;
        const float a1 = ok1 ? alpha[r1] : 0.0f;
        for (int b = 0; b < B; ++b) {
            float4 v0 = e0, v1 = e1;
            if ((m0 >> b) & 1u) {
                int jl = 0;
                #pragma unroll 1
                for (int j = 0; j < n; ++j)
                    if (sidx[b * n + j] == r0) jl = j;       // last-write-wins
                const float4 f = feat[(size_t)(b * n + jl) * SEGS + seg];
                const float om = 1.0f - a0;
                v0.x = om * e0.x + a0 * f.x; v0.y = om * e0.y + a0 * f.y;
                v0.z = om * e0.z + a0 * f.z; v0.w = om * e0.w + a0 * f.w;
            }
            if ((m1 >> b) & 1u) {
                int jl = 0;
                #pragma unroll 1
                for (int j = 0; j < n; ++j)
                    if (sidx[b * n + j] == r1) jl = j;
                const float4 f = feat[(size_t)(b * n + jl) * SEGS + seg];
                const float om = 1.0f - a1;
                v1.x = om * e1.x + a1 * f.x; v1.y = om * e1.y + a1 * f.y;
                v1.z = om * e1.z + a1 * f.z; v1.w = om * e1.w + a1 * f.w;
            }
            if (ok0) po0[b * bstride] = v0;
            if (ok1) po1[b * bstride] = v1;
        }
    }
}

extern "C" void kernel_launch(void* const* d_in, const int* in_sizes, int n_in,
                              void* d_out, int out_size, void* d_ws, size_t ws_size,
                              hipStream_t stream) {
    const int*   nodes = (const int*)d_in[0];
    const float* feat  = (const float*)d_in[1];
    const float* emb   = (const float*)d_in[2];
    const float* alpha = (const float*)d_in[3];

    const int items = in_sizes[3];                 // 50000
    const int B     = out_size / (items * DIM);    // 16
    const int n     = in_sizes[0] / B;             // 50

    const int grid = (items + RPB - 1) / RPB;      // 1563
    const size_t lds_bytes = (size_t)(RPB + B * n) * sizeof(unsigned int); // ~3.3 KB

    if (B == 16) {
        ggu_kernel<16><<<grid, BLOCK, lds_bytes, stream>>>(
            nodes, (const float4*)feat, (const float4*)emb, alpha,
            (float4*)d_out, items, n, B);
    } else {
        ggu_kernel<0><<<grid, BLOCK, lds_bytes, stream>>>(
            nodes, (const float4*)feat, (const float4*)emb, alpha,
            (float4*)d_out, items, n, B);
    }
}